// Round 2
// baseline (768.473 us; speedup 1.0000x reference)
//
#include <hip/hip_runtime.h>
#include <stdint.h>

typedef unsigned short u16;
typedef unsigned int   u32;

#define B_SZ  32
#define CIN   256
#define NPIX  3136      // 56*56
#define COUT  256
#define HID   64
#define NBANK 4
#define BANK_SZ 589824  // COUT*CIN*9 elements per bank (fp32)
#define WF_N  18874368  // premixed elements per half: 32*16*9*8*512

// pre-split x planes: [b][cis(8)][row(60)][col(64)][ci(32)] u16, hi then lo
#define XROWS 60
#define XSP_HALF 31457280ull    // 32*8*60*64*32 elements per half

typedef short bf16x8 __attribute__((ext_vector_type(8)));
typedef float f32x4  __attribute__((ext_vector_type(4)));

struct __align__(16) U4 { u32 x, y, z, w; };
struct __align__(16) F4 { float x, y, z, w; };

__device__ __forceinline__ float bf2f(u16 u) {
    union { u32 i; float f; } v; v.i = ((u32)u) << 16; return v.f;
}
__device__ __forceinline__ u16 f2bf(float f) {
    union { float f; u32 i; } v; v.f = f;
    u32 u = v.i;
    return (u16)((u + 0x7FFFu + ((u >> 16) & 1u)) >> 16);   // RNE
}

// ---------------------------------------------------------------- mean ----
__global__ __launch_bounds__(64) void k_mean(const float* __restrict__ x,
                                             float* __restrict__ vout) {
    int bc = blockIdx.x;
    const F4* p = (const F4*)(x + (size_t)bc * NPIX);
    float s = 0.f;
    for (int o = threadIdx.x; o < 784; o += 64) {   // 784*4 = 3136
        F4 u = p[o];
        s += u.x + u.y + u.z + u.w;
    }
    #pragma unroll
    for (int off = 32; off > 0; off >>= 1) s += __shfl_down(s, off, 64);
    if (threadIdx.x == 0) vout[bc] = s * (1.0f / 3136.0f);
}

// -------------------------------------------------------------- router ----
__global__ __launch_bounds__(64) void k_router(const float* __restrict__ v,
        const float* __restrict__ fc1w, const float* __restrict__ fc1b,
        const float* __restrict__ fc2w, const float* __restrict__ fc2b,
        float* __restrict__ aout) {
    int b = blockIdx.x, j = threadIdx.x;
    __shared__ float hl[HID];
    __shared__ float lg[NBANK];
    const float* vb = v + b * CIN;
    float acc = fc1b[j];
    const F4* wrow = (const F4*)(fc1w + j * CIN);
    for (int o = 0; o < 64; ++o) {
        F4 u = wrow[o];
        acc += vb[o * 4 + 0] * u.x + vb[o * 4 + 1] * u.y
             + vb[o * 4 + 2] * u.z + vb[o * 4 + 3] * u.w;
    }
    hl[j] = acc > 0.f ? acc : 0.f;
    __syncthreads();
    if (j < NBANK) {
        float l = fc2b[j];
        for (int t = 0; t < HID; ++t) l += hl[t] * fc2w[j * HID + t];
        lg[j] = l;
    }
    __syncthreads();
    if (j == 0) {
        float m = lg[0];
        for (int k = 1; k < NBANK; ++k) m = fmaxf(m, lg[k]);
        float e[NBANK], se = 0.f;
        for (int k = 0; k < NBANK; ++k) { e[k] = expf(lg[k] - m); se += e[k]; }
        for (int k = 0; k < NBANK; ++k) aout[b * NBANK + k] = e[k] / se;
    }
}

// --------------------------------------------------------------- split ----
// Pre-split x (fp32) into bf16 hi/lo planes in the conv's LDS staging layout:
//   xsp[half][b][cis][row][col][ci], row = hin+1 (rows 0,57,58,59 zero),
//   col = win+1 (cols 0,57..63 zero). One block per (b,cis,row).
__global__ __launch_bounds__(256) void k_split(const float* __restrict__ x,
                                               u16* __restrict__ xsp) {
    const int blk = blockIdx.x;            // ((b*8)+cis)*60 + row
    const int row = blk % XROWS;
    const int bc  = blk / XROWS;
    const int b   = bc >> 3, cis = bc & 7;
    const int t   = threadIdx.x;
    const size_t obase = (size_t)blk * 2048;   // 64*32 elements per row
    const int hin = row - 1;
    if (hin < 0 || hin >= 56) {
        U4 z; z.x = 0; z.y = 0; z.z = 0; z.w = 0;
        *(U4*)(xsp + obase + (size_t)t * 8) = z;
        *(U4*)(xsp + XSP_HALF + obase + (size_t)t * 8) = z;
        return;
    }
    __shared__ float ls[32 * 57];   // [ci][56 + pad]
    const float* xb = x + ((size_t)b * CIN + cis * 32) * NPIX + hin * 56;
    for (int idx = t; idx < 448; idx += 256) {     // 32 ci x 14 F4
        int ci = idx / 14, o = idx - ci * 14;
        F4 u = *(const F4*)(xb + (size_t)ci * NPIX + o * 4);
        float* d = &ls[ci * 57 + o * 4];
        d[0] = u.x; d[1] = u.y; d[2] = u.z; d[3] = u.w;
    }
    __syncthreads();
    const int ci2 = (t & 15) * 2;     // ci pair
    const int cg  = t >> 4;           // 0..15
    #pragma unroll
    for (int k = 0; k < 4; ++k) {
        int col = cg + k * 16;
        int win = col - 1;
        float v0 = 0.f, v1 = 0.f;
        if (win >= 0 && win < 56) {
            v0 = ls[ci2 * 57 + win];
            v1 = ls[(ci2 + 1) * 57 + win];
        }
        u16 h0 = f2bf(v0), h1 = f2bf(v1);
        u16 l0 = f2bf(v0 - bf2f(h0)), l1 = f2bf(v1 - bf2f(h1));
        *(u32*)(xsp + obase + col * 32 + ci2) = (u32)h0 | ((u32)h1 << 16);
        *(u32*)(xsp + XSP_HALF + obase + col * 32 + ci2) = (u32)l0 | ((u32)l1 << 16);
    }
}

// -------------------------------------------------------------- premix ----
#define PM_PAD 145
__global__ __launch_bounds__(256) void k_premix(const float* __restrict__ bank,
        const float* __restrict__ aws, u16* __restrict__ wf) {
    int cof   = blockIdx.x >> 4;
    int cis16 = blockIdx.x & 15;
    __shared__ float lw[64 * PM_PAD];
    for (int idx = threadIdx.x; idx < 64 * 144; idx += 256) {
        int s = idx / 144;
        int e = idx - s * 144;
        int k = s >> 4, co_l = s & 15;
        lw[s * PM_PAD + e] =
            bank[(size_t)(k * COUT + cof * 16 + co_l) * (CIN * 9) + cis16 * 144 + e];
    }
    __syncthreads();
    const int cis   = cis16 >> 1;
    const int qbase = (cis16 & 1) * 2;
    for (int b = 0; b < B_SZ; ++b) {
        float a0 = aws[b * 4 + 0], a1 = aws[b * 4 + 1];
        float a2 = aws[b * 4 + 2], a3 = aws[b * 4 + 3];
        for (int o = threadIdx.x; o < 288; o += 256) {
            int t  = o >> 5;
            int hlane = o & 31;
            int lane  = qbase * 16 + hlane;
            int m = lane & 15, q = lane >> 4;
            int q_loc = q - qbase;
            u16 ph[8], plo[8];
            #pragma unroll
            for (int jj = 0; jj < 8; ++jj) {
                int ee = (q_loc * 8 + jj) * 9 + t;
                float w = a0 * lw[(0 * 16 + m) * PM_PAD + ee]
                        + a1 * lw[(1 * 16 + m) * PM_PAD + ee]
                        + a2 * lw[(2 * 16 + m) * PM_PAD + ee]
                        + a3 * lw[(3 * 16 + m) * PM_PAD + ee];
                u16 h = f2bf(w);
                ph[jj]  = h;
                plo[jj] = f2bf(w - bf2f(h));
            }
            size_t off = ((((size_t)b * 16 + cof) * 9 + t) * 8 + cis) * 512
                       + (size_t)lane * 8;
            U4 uh, ul;
            uh.x = (u32)ph[0] | ((u32)ph[1] << 16);
            uh.y = (u32)ph[2] | ((u32)ph[3] << 16);
            uh.z = (u32)ph[4] | ((u32)ph[5] << 16);
            uh.w = (u32)ph[6] | ((u32)ph[7] << 16);
            ul.x = (u32)plo[0] | ((u32)plo[1] << 16);
            ul.y = (u32)plo[2] | ((u32)plo[3] << 16);
            ul.z = (u32)plo[4] | ((u32)plo[5] << 16);
            ul.w = (u32)plo[6] | ((u32)plo[7] << 16);
            *(U4*)(wf + off)        = uh;
            *(U4*)(wf + WF_N + off) = ul;
        }
    }
}

// ---------------------------------------------------------------- conv ----
// MODE 2: premixed weights + pre-split x, T14 reg-staged pipeline:
//         barrier -> ds_write(regs) -> barrier -> issue loads(cis+1) -> MFMA
// MODE 1: premixed weights, in-kernel fp32->bf16 split staging (fallback)
// MODE 0: on-the-fly weights + in-kernel staging (fallback)
template<int MODE>
__global__ __launch_bounds__(256, 2) void k_conv(
        const float* __restrict__ x,
        const u16* __restrict__ wh_t,     // premixed hi; lo at +WF_N
        const u16* __restrict__ xsp,      // pre-split x hi; lo at +XSP_HALF
        const float* __restrict__ bank,
        const float* __restrict__ aws,
        float* __restrict__ out) {
    constexpr int CSTR = (MODE == 2) ? 64 : 58;      // LDS col stride
    constexpr int PLB  = (MODE == 2) ? 24576 : 22272; // plane offset bytes
    __shared__ u16 xs[2][(MODE == 2) ? 12288 : 11136];

    const int pt    = blockIdx.x;   // 0..24 pixel tile (128 pixels)
    const int coblk = blockIdx.y;   // 0..1  co half (128 co)
    const int b     = blockIdx.z;   // 0..31

    const int tid  = threadIdx.x;
    const int wave = tid >> 6;
    const int lane = tid & 63;
    const int wm = wave >> 1, wn = wave & 1;

    const int pix0 = pt * 128;
    const int h0   = pix0 / 56;
    const int rlo  = h0 - 1;

    const float* xb = x + (size_t)b * CIN * NPIX;

    int bbase[4], pl[4];
    #pragma unroll
    for (int nf = 0; nf < 4; ++nf) {
        int p = pix0 + wn * 64 + nf * 16 + (lane & 15);
        pl[nf] = p;
        int pc = p < NPIX ? p : NPIX - 1;
        int hp = pc / 56, wp = pc - (pc / 56) * 56;
        bbase[nf] = ((hp - h0) * CSTR + wp) * 64 + (lane >> 4) * 16;   // bytes
    }

    const int cof_base = coblk * 8 + wm * 4;
    float a0 = 0.f, a1 = 0.f, a2 = 0.f, a3 = 0.f;
    if (MODE == 0) {
        a0 = aws[b * 4 + 0]; a1 = aws[b * 4 + 1];
        a2 = aws[b * 4 + 2]; a3 = aws[b * 4 + 3];
    }

    f32x4 acc[4][4];
    #pragma unroll
    for (int i = 0; i < 4; ++i)
        #pragma unroll
        for (int j = 0; j < 4; ++j) { f32x4 z = {0.f, 0.f, 0.f, 0.f}; acc[i][j] = z; }

    // ---- T14 prefetch registers (MODE 2): 12 x 16B per thread ----
    U4 stg[12];
    if (MODE == 2) {
        const size_t bel = (((size_t)b * 8 + 0) * XROWS + h0) * 2048 + (size_t)tid * 8;
        const u16* g0 = xsp + bel;
        const u16* g1 = xsp + XSP_HALF + bel;
        #pragma unroll
        for (int c = 0; c < 6; ++c) stg[c]     = *(const U4*)(g0 + c * 2048);
        #pragma unroll
        for (int c = 0; c < 6; ++c) stg[6 + c] = *(const U4*)(g1 + c * 2048);
    }

    for (int cis = 0; cis < 8; ++cis) {
        const int ci0 = cis * 32;
        __syncthreads();   // (A) all waves done reading xs; prefetch landed
        if (MODE == 2) {
            // ---- write-late: regs -> LDS (linear, conflict-free) ----
            u16* l0 = (u16*)xs;
            #pragma unroll
            for (int c = 0; c < 12; ++c)
                *(U4*)(l0 + (size_t)c * 2048 + tid * 8) = stg[c];
            __syncthreads();   // (B) xs ready; nothing in flight -> cheap
            // ---- issue-early: loads for cis+1, in flight across t-loop ----
            if (cis < 7) {
                const size_t bel = (((size_t)b * 8 + cis + 1) * XROWS + h0) * 2048
                                 + (size_t)tid * 8;
                const u16* g0 = xsp + bel;
                const u16* g1 = xsp + XSP_HALF + bel;
                #pragma unroll
                for (int c = 0; c < 6; ++c) stg[c]     = *(const U4*)(g0 + c * 2048);
                #pragma unroll
                for (int c = 0; c < 6; ++c) stg[6 + c] = *(const U4*)(g1 + c * 2048);
            }
        } else {
            // ---- stage + split: fp32 x -> bf16 hi/lo planes ----
            for (int idx = tid; idx < 1392; idx += 256) {
                int oct = idx / 348;
                int rc  = idx - oct * 348;
                int row = rc / 58, col = rc - row * 58;
                int hin = rlo + row, win = col - 1;
                U4 uh; uh.x = 0; uh.y = 0; uh.z = 0; uh.w = 0;
                U4 ul = uh;
                if (hin >= 0 && hin < 56 && win >= 0 && win < 56) {
                    const float* g = xb + (size_t)(ci0 + oct * 8) * NPIX + hin * 56 + win;
                    u16 eh[8], el[8];
                    #pragma unroll
                    for (int i = 0; i < 8; ++i) {
                        float v = g[(size_t)i * NPIX];
                        u16 h = f2bf(v);
                        eh[i] = h;
                        el[i] = f2bf(v - bf2f(h));
                    }
                    uh.x = (u32)eh[0] | ((u32)eh[1] << 16);
                    uh.y = (u32)eh[2] | ((u32)eh[3] << 16);
                    uh.z = (u32)eh[4] | ((u32)eh[5] << 16);
                    uh.w = (u32)eh[6] | ((u32)eh[7] << 16);
                    ul.x = (u32)el[0] | ((u32)el[1] << 16);
                    ul.y = (u32)el[2] | ((u32)el[3] << 16);
                    ul.z = (u32)el[4] | ((u32)el[5] << 16);
                    ul.w = (u32)el[6] | ((u32)el[7] << 16);
                }
                *(U4*)(&xs[0][rc * 32 + oct * 8]) = uh;
                *(U4*)(&xs[1][rc * 32 + oct * 8]) = ul;
            }
            __syncthreads();
        }

        #pragma unroll
        for (int t = 0; t < 9; ++t) {
            const int ty = t / 3, tx = t - (t / 3) * 3;
            bf16x8 ah[4], al[4];
            if (MODE >= 1) {
                #pragma unroll
                for (int mf = 0; mf < 4; ++mf) {
                    size_t off = ((((size_t)b * 16 + cof_base + mf) * 9 + t) * 8 + cis) * 512
                               + (size_t)lane * 8;
                    ah[mf] = *(const bf16x8*)(wh_t + off);
                    al[mf] = *(const bf16x8*)(wh_t + WF_N + off);
                }
            } else {
                #pragma unroll
                for (int mf = 0; mf < 4; ++mf) {
                    int co = coblk * 128 + wm * 64 + mf * 16 + (lane & 15);
                    int q = lane >> 4;
                    u16 ph[8], plo[8];
                    #pragma unroll
                    for (int jj = 0; jj < 8; ++jj) {
                        int ci = ci0 + q * 8 + jj;
                        size_t base = ((size_t)co * CIN + ci) * 9 + t;
                        float w = a0 * bank[base]
                                + a1 * bank[base + BANK_SZ]
                                + a2 * bank[base + 2 * BANK_SZ]
                                + a3 * bank[base + 3 * BANK_SZ];
                        u16 h = f2bf(w);
                        ph[jj]  = h;
                        plo[jj] = f2bf(w - bf2f(h));
                    }
                    union { U4 u; bf16x8 v; } pu;
                    pu.u.x = (u32)ph[0] | ((u32)ph[1] << 16);
                    pu.u.y = (u32)ph[2] | ((u32)ph[3] << 16);
                    pu.u.z = (u32)ph[4] | ((u32)ph[5] << 16);
                    pu.u.w = (u32)ph[6] | ((u32)ph[7] << 16);
                    ah[mf] = pu.v;
                    pu.u.x = (u32)plo[0] | ((u32)plo[1] << 16);
                    pu.u.y = (u32)plo[2] | ((u32)plo[3] << 16);
                    pu.u.z = (u32)plo[4] | ((u32)plo[5] << 16);
                    pu.u.w = (u32)plo[6] | ((u32)plo[7] << 16);
                    al[mf] = pu.v;
                }
            }
            const int toff = (ty * CSTR + tx) * 64;   // bytes
            const char* base = (const char*)&xs[0][0];
            #pragma unroll
            for (int nf = 0; nf < 4; ++nf) {
                bf16x8 bh = *(const bf16x8*)(base + bbase[nf] + toff);
                bf16x8 bl = *(const bf16x8*)(base + PLB + bbase[nf] + toff);
                #pragma unroll
                for (int mf = 0; mf < 4; ++mf) {
                    acc[mf][nf] = __builtin_amdgcn_mfma_f32_16x16x32_bf16(
                        ah[mf], bh, acc[mf][nf], 0, 0, 0);
                    acc[mf][nf] = __builtin_amdgcn_mfma_f32_16x16x32_bf16(
                        ah[mf], bl, acc[mf][nf], 0, 0, 0);
                    acc[mf][nf] = __builtin_amdgcn_mfma_f32_16x16x32_bf16(
                        al[mf], bh, acc[mf][nf], 0, 0, 0);
                }
            }
        }
    }

    // ---- epilogue: C/D layout col(pixel)=lane&15, row(co)=(lane>>4)*4+r ----
    float* ob = out + (size_t)b * COUT * NPIX;
    #pragma unroll
    for (int mf = 0; mf < 4; ++mf) {
        int cobase = coblk * 128 + wm * 64 + mf * 16 + (lane >> 4) * 4;
        #pragma unroll
        for (int nf = 0; nf < 4; ++nf) {
            int p = pl[nf];
            if (p < NPIX) {
                #pragma unroll
                for (int r = 0; r < 4; ++r)
                    ob[(size_t)(cobase + r) * NPIX + p] = acc[mf][nf][r];
            }
        }
    }
}

// -------------------------------------------------------------- launch ----
extern "C" void kernel_launch(void* const* d_in, const int* in_sizes, int n_in,
                              void* d_out, int out_size, void* d_ws, size_t ws_size,
                              hipStream_t stream) {
    const float* x    = (const float*)d_in[0];
    const float* bank = (const float*)d_in[1];
    const float* fc1w = (const float*)d_in[2];
    const float* fc1b = (const float*)d_in[3];
    const float* fc2w = (const float*)d_in[4];
    const float* fc2b = (const float*)d_in[5];
    float* out = (float*)d_out;

    float* a_ws = (float*)d_ws;                 // 128 floats @ 0
    float* v_ws = (float*)d_ws + 128;           // 8192 floats @ 512B
    u16*   wf   = (u16*)((char*)d_ws + 65536);  // 2 x 37.75 MB premixed hi/lo
    u16*   xsp  = (u16*)((char*)d_ws + 65536 + (size_t)WF_N * 2 * sizeof(u16));

    const size_t need1 = (size_t)65536 + (size_t)WF_N * 2 * sizeof(u16);
    const size_t need2 = need1 + (size_t)XSP_HALF * 2 * sizeof(u16);

    k_mean<<<dim3(B_SZ * CIN), dim3(64), 0, stream>>>(x, v_ws);
    k_router<<<dim3(B_SZ), dim3(64), 0, stream>>>(v_ws, fc1w, fc1b, fc2w, fc2b, a_ws);

    dim3 grid(25, 2, B_SZ);
    if (ws_size >= need2) {
        k_premix<<<dim3(256), dim3(256), 0, stream>>>(bank, a_ws, wf);
        k_split<<<dim3(B_SZ * 8 * XROWS), dim3(256), 0, stream>>>(x, xsp);
        k_conv<2><<<grid, dim3(256), 0, stream>>>(x, wf, xsp, bank, a_ws, out);
    } else if (ws_size >= need1) {
        k_premix<<<dim3(256), dim3(256), 0, stream>>>(bank, a_ws, wf);
        k_conv<1><<<grid, dim3(256), 0, stream>>>(x, wf, wf, bank, a_ws, out);
    } else {
        k_conv<0><<<grid, dim3(256), 0, stream>>>(x, wf, wf, bank, a_ws, out);
    }
}

// Round 3
// 741.468 us; speedup vs baseline: 1.0364x; 1.0364x over previous
//
#include <hip/hip_runtime.h>
#include <stdint.h>

typedef unsigned short u16;
typedef unsigned int   u32;

#define B_SZ  32
#define CIN   256
#define NPIX  3136      // 56*56
#define COUT  256
#define HID   64
#define NBANK 4
#define BANK_SZ 589824  // COUT*CIN*9 elements per bank (fp32)
#define WF_N  18874368  // premixed elements per half: 32*16*9*8*512

// pre-split x planes: [b][cis(8)][row(64)][ciq(4)][col(64)][ci8(8)] u16
// (row = hin+1; rows 0 and 57..63 zero; col = win+1, cols 0,57..63 zero)
#define XROWS 64
#define XSP_HALF 33554432ull    // 32*8*64*2048 elements per half

typedef short bf16x8 __attribute__((ext_vector_type(8)));
typedef float f32x4  __attribute__((ext_vector_type(4)));

struct __align__(16) U4 { u32 x, y, z, w; };
struct __align__(16) F4 { float x, y, z, w; };

__device__ __forceinline__ float bf2f(u16 u) {
    union { u32 i; float f; } v; v.i = ((u32)u) << 16; return v.f;
}
__device__ __forceinline__ u16 f2bf(float f) {
    union { float f; u32 i; } v; v.f = f;
    u32 u = v.i;
    return (u16)((u + 0x7FFFu + ((u >> 16) & 1u)) >> 16);   // RNE
}

__device__ __forceinline__ void gload_lds16(const u16* g, u16* l) {
    __builtin_amdgcn_global_load_lds(
        (const __attribute__((address_space(1))) void*)g,
        (__attribute__((address_space(3))) void*)l, 16, 0, 0);
}

// ---------------------------------------------------------------- mean ----
__global__ __launch_bounds__(64) void k_mean(const float* __restrict__ x,
                                             float* __restrict__ vout) {
    int bc = blockIdx.x;
    const F4* p = (const F4*)(x + (size_t)bc * NPIX);
    float s = 0.f;
    for (int o = threadIdx.x; o < 784; o += 64) {   // 784*4 = 3136
        F4 u = p[o];
        s += u.x + u.y + u.z + u.w;
    }
    #pragma unroll
    for (int off = 32; off > 0; off >>= 1) s += __shfl_down(s, off, 64);
    if (threadIdx.x == 0) vout[bc] = s * (1.0f / 3136.0f);
}

// -------------------------------------------------------------- router ----
__global__ __launch_bounds__(64) void k_router(const float* __restrict__ v,
        const float* __restrict__ fc1w, const float* __restrict__ fc1b,
        const float* __restrict__ fc2w, const float* __restrict__ fc2b,
        float* __restrict__ aout) {
    int b = blockIdx.x, j = threadIdx.x;
    __shared__ float hl[HID];
    __shared__ float lg[NBANK];
    const float* vb = v + b * CIN;
    float acc = fc1b[j];
    const F4* wrow = (const F4*)(fc1w + j * CIN);
    for (int o = 0; o < 64; ++o) {
        F4 u = wrow[o];
        acc += vb[o * 4 + 0] * u.x + vb[o * 4 + 1] * u.y
             + vb[o * 4 + 2] * u.z + vb[o * 4 + 3] * u.w;
    }
    hl[j] = acc > 0.f ? acc : 0.f;
    __syncthreads();
    if (j < NBANK) {
        float l = fc2b[j];
        for (int t = 0; t < HID; ++t) l += hl[t] * fc2w[j * HID + t];
        lg[j] = l;
    }
    __syncthreads();
    if (j == 0) {
        float m = lg[0];
        for (int k = 1; k < NBANK; ++k) m = fmaxf(m, lg[k]);
        float e[NBANK], se = 0.f;
        for (int k = 0; k < NBANK; ++k) { e[k] = expf(lg[k] - m); se += e[k]; }
        for (int k = 0; k < NBANK; ++k) aout[b * NBANK + k] = e[k] / se;
    }
}

// --------------------------------------------------------------- split ----
// One block per (b, cis, row). Row layout: [ciq(4)][col(64)][ci8(8)] u16
// so a wave's 64 lanes read consecutive 16B atoms (conflict-free ds_read).
__global__ __launch_bounds__(256) void k_split(const float* __restrict__ x,
                                               u16* __restrict__ xsp) {
    const int blk = blockIdx.x;            // ((b*8)+cis)*64 + row
    const int row = blk & 63;
    const int bc  = blk >> 6;
    const int b   = bc >> 3, cis = bc & 7;
    const int t   = threadIdx.x;
    const size_t obase = (size_t)blk * 2048;   // 2048 u16 per row
    const int hin = row - 1;
    if (hin < 0 || hin >= 56) {
        U4 z; z.x = 0; z.y = 0; z.z = 0; z.w = 0;
        *(U4*)(xsp + obase + (size_t)t * 8) = z;
        *(U4*)(xsp + XSP_HALF + obase + (size_t)t * 8) = z;
        return;
    }
    __shared__ float ls[32 * 57];   // [ci][56 + pad]
    const float* xb = x + ((size_t)b * CIN + cis * 32) * NPIX + hin * 56;
    for (int idx = t; idx < 448; idx += 256) {     // 32 ci x 14 F4
        int ci = idx / 14, o = idx - ci * 14;
        F4 u = *(const F4*)(xb + (size_t)ci * NPIX + o * 4);
        float* d = &ls[ci * 57 + o * 4];
        d[0] = u.x; d[1] = u.y; d[2] = u.z; d[3] = u.w;
    }
    __syncthreads();
    const int ci2 = (t & 15) * 2;     // even ci
    const int cg  = t >> 4;           // 0..15
    const int ciq = ci2 >> 3;
    const int cil = ci2 & 7;
    #pragma unroll
    for (int k = 0; k < 4; ++k) {
        int col = cg + k * 16;
        int win = col - 1;
        float v0 = 0.f, v1 = 0.f;
        if (win >= 0 && win < 56) {
            v0 = ls[ci2 * 57 + win];
            v1 = ls[(ci2 + 1) * 57 + win];
        }
        u16 h0 = f2bf(v0), h1 = f2bf(v1);
        u16 l0 = f2bf(v0 - bf2f(h0)), l1 = f2bf(v1 - bf2f(h1));
        size_t pos = obase + (size_t)(ciq * 64 + col) * 8 + cil;
        *(u32*)(xsp + pos)            = (u32)h0 | ((u32)h1 << 16);
        *(u32*)(xsp + XSP_HALF + pos) = (u32)l0 | ((u32)l1 << 16);
    }
}

// -------------------------------------------------------------- premix ----
// grid (256, 32): x = cof*16 + cis16, y = b.
#define PM_PAD 145
__global__ __launch_bounds__(256) void k_premix(const float* __restrict__ bank,
        const float* __restrict__ aws, u16* __restrict__ wf) {
    int cof   = blockIdx.x >> 4;
    int cis16 = blockIdx.x & 15;
    int b     = blockIdx.y;
    __shared__ float lw[64 * PM_PAD];
    for (int idx = threadIdx.x; idx < 64 * 144; idx += 256) {
        int s = idx / 144;
        int e = idx - s * 144;
        int k = s >> 4, co_l = s & 15;
        lw[s * PM_PAD + e] =
            bank[(size_t)(k * COUT + cof * 16 + co_l) * (CIN * 9) + cis16 * 144 + e];
    }
    __syncthreads();
    const int cis   = cis16 >> 1;
    const int qbase = (cis16 & 1) * 2;
    float a0 = aws[b * 4 + 0], a1 = aws[b * 4 + 1];
    float a2 = aws[b * 4 + 2], a3 = aws[b * 4 + 3];
    for (int o = threadIdx.x; o < 288; o += 256) {
        int t  = o >> 5;
        int hlane = o & 31;
        int lane  = qbase * 16 + hlane;
        int m = lane & 15, q = lane >> 4;
        int q_loc = q - qbase;
        u16 ph[8], plo[8];
        #pragma unroll
        for (int jj = 0; jj < 8; ++jj) {
            int ee = (q_loc * 8 + jj) * 9 + t;
            float w = a0 * lw[(0 * 16 + m) * PM_PAD + ee]
                    + a1 * lw[(1 * 16 + m) * PM_PAD + ee]
                    + a2 * lw[(2 * 16 + m) * PM_PAD + ee]
                    + a3 * lw[(3 * 16 + m) * PM_PAD + ee];
            u16 h = f2bf(w);
            ph[jj]  = h;
            plo[jj] = f2bf(w - bf2f(h));
        }
        size_t off = ((((size_t)b * 16 + cof) * 9 + t) * 8 + cis) * 512
                   + (size_t)lane * 8;
        U4 uh, ul;
        uh.x = (u32)ph[0] | ((u32)ph[1] << 16);
        uh.y = (u32)ph[2] | ((u32)ph[3] << 16);
        uh.z = (u32)ph[4] | ((u32)ph[5] << 16);
        uh.w = (u32)ph[6] | ((u32)ph[7] << 16);
        ul.x = (u32)plo[0] | ((u32)plo[1] << 16);
        ul.y = (u32)plo[2] | ((u32)plo[3] << 16);
        ul.z = (u32)plo[4] | ((u32)plo[5] << 16);
        ul.w = (u32)plo[6] | ((u32)plo[7] << 16);
        *(U4*)(wf + off)        = uh;
        *(U4*)(wf + WF_N + off) = ul;
    }
}

// ---------------------------------------------------------------- conv ----
// 256-pixel tile, half-plane (hi/lo) double-buffered pipeline.
// Per cis: [wait+bar][issue lo->buf1][compute hi on buf0: wh*xh + wl*xh]
//          [wait+bar][issue hi(cis+1)->buf0][compute lo on buf1: wh*xl]
// Raw s_barrier + manual waitcnt: stage loads stay in flight across the
// whole opposite compute phase (no compiler vmcnt(0)-before-barrier drain).
__global__ __launch_bounds__(256, 2) void k_conv2(
        const u16* __restrict__ wh_t,     // premixed hi; lo at +WF_N
        const u16* __restrict__ xsp,      // pre-split x hi; lo at +XSP_HALF
        float* __restrict__ out) {
    __shared__ u16 xbuf[2][16384];        // 2 x 32 KiB planes

    const int pt    = blockIdx.x;   // 0..12 pixel tile (256 pixels)
    const int coblk = blockIdx.y;   // 0..1  co half (128 co)
    const int b     = blockIdx.z;   // 0..31

    const int tid  = threadIdx.x;
    const int wave = tid >> 6;
    const int lane = tid & 63;
    const int wm = wave >> 1, wn = wave & 1;

    const int pix0 = pt * 256;
    const int h0   = pix0 / 56;

    // staging source base for (b, cis=0, hi); cis step = 131072 u16
    const size_t rowbase = (((size_t)b * 8) * 64 + h0) * 2048;

    int bb[8], pl[8];
    #pragma unroll
    for (int nf = 0; nf < 8; ++nf) {
        int p = pix0 + wn * 128 + nf * 16 + (lane & 15);
        pl[nf] = p;
        int pc = p < NPIX ? p : NPIX - 1;
        int hp = pc / 56, wp = pc - (pc / 56) * 56;
        // byte offset: [(row)(4 ciq)(64 col)] * 16B atoms
        bb[nf] = ((hp - h0) * 256 + (lane >> 4) * 64 + wp) * 16;
    }

    const u16* wbase = wh_t
        + ((size_t)b * 16 + coblk * 8 + wm * 4) * (9 * 8 * 512)
        + (size_t)lane * 8;

    f32x4 acc[4][8];
    #pragma unroll
    for (int i = 0; i < 4; ++i)
        #pragma unroll
        for (int j = 0; j < 8; ++j) { f32x4 z = {0.f, 0.f, 0.f, 0.f}; acc[i][j] = z; }

    // ---- prologue: stage (cis0, hi) -> buf0 ----
    {
        const u16* sb = xsp + rowbase;
        #pragma unroll
        for (int c = wave; c < 32; c += 4)
            gload_lds16(sb + c * 512 + lane * 8, &xbuf[0][c * 512 + lane * 8]);
    }

    for (int cis = 0; cis < 8; ++cis) {
        // ================= HI phase (x-hi plane in buf0) =================
        asm volatile("s_waitcnt vmcnt(0) lgkmcnt(0)" ::: "memory");
        __builtin_amdgcn_s_barrier();
        __builtin_amdgcn_sched_barrier(0);
        {   // issue lo-plane of this cis -> buf1
            const u16* sb = xsp + XSP_HALF + rowbase + (size_t)cis * 131072;
            #pragma unroll
            for (int c = wave; c < 32; c += 4)
                gload_lds16(sb + c * 512 + lane * 8, &xbuf[1][c * 512 + lane * 8]);
        }
        __builtin_amdgcn_sched_barrier(0);
        #pragma unroll
        for (int t = 0; t < 9; ++t) {
            const int ty = t / 3, tx = t - ty * 3;
            const int toff = ty * 4096 + tx * 16;
            bf16x8 ah[4], al[4];
            #pragma unroll
            for (int mf = 0; mf < 4; ++mf) {
                size_t off = (size_t)((mf * 9 + t) * 8 + cis) * 512;
                ah[mf] = *(const bf16x8*)(wbase + off);
                al[mf] = *(const bf16x8*)(wbase + WF_N + off);
            }
            #pragma unroll
            for (int nf = 0; nf < 8; ++nf) {
                bf16x8 bx = *(const bf16x8*)((const char*)&xbuf[0][0] + bb[nf] + toff);
                #pragma unroll
                for (int mf = 0; mf < 4; ++mf) {
                    acc[mf][nf] = __builtin_amdgcn_mfma_f32_16x16x32_bf16(
                        ah[mf], bx, acc[mf][nf], 0, 0, 0);
                    acc[mf][nf] = __builtin_amdgcn_mfma_f32_16x16x32_bf16(
                        al[mf], bx, acc[mf][nf], 0, 0, 0);
                }
            }
        }
        // ================= LO phase (x-lo plane in buf1) =================
        asm volatile("s_waitcnt vmcnt(0) lgkmcnt(0)" ::: "memory");
        __builtin_amdgcn_s_barrier();
        __builtin_amdgcn_sched_barrier(0);
        if (cis < 7) {   // issue hi-plane of cis+1 -> buf0
            const u16* sb = xsp + rowbase + (size_t)(cis + 1) * 131072;
            #pragma unroll
            for (int c = wave; c < 32; c += 4)
                gload_lds16(sb + c * 512 + lane * 8, &xbuf[0][c * 512 + lane * 8]);
        }
        __builtin_amdgcn_sched_barrier(0);
        #pragma unroll
        for (int t = 0; t < 9; ++t) {
            const int ty = t / 3, tx = t - ty * 3;
            const int toff = ty * 4096 + tx * 16;
            bf16x8 ah[4];
            #pragma unroll
            for (int mf = 0; mf < 4; ++mf) {
                size_t off = (size_t)((mf * 9 + t) * 8 + cis) * 512;
                ah[mf] = *(const bf16x8*)(wbase + off);
            }
            #pragma unroll
            for (int nf = 0; nf < 8; ++nf) {
                bf16x8 bx = *(const bf16x8*)((const char*)&xbuf[1][0] + bb[nf] + toff);
                #pragma unroll
                for (int mf = 0; mf < 4; ++mf) {
                    acc[mf][nf] = __builtin_amdgcn_mfma_f32_16x16x32_bf16(
                        ah[mf], bx, acc[mf][nf], 0, 0, 0);
                }
            }
        }
    }

    // ---- epilogue: C/D layout col(pixel)=lane&15, row(co)=(lane>>4)*4+r ----
    float* ob = out + (size_t)b * COUT * NPIX;
    #pragma unroll
    for (int mf = 0; mf < 4; ++mf) {
        int cobase = coblk * 128 + wm * 64 + mf * 16 + (lane >> 4) * 4;
        #pragma unroll
        for (int nf = 0; nf < 8; ++nf) {
            int p = pl[nf];
            if (p < NPIX) {
                #pragma unroll
                for (int r = 0; r < 4; ++r)
                    ob[(size_t)(cobase + r) * NPIX + p] = acc[mf][nf][r];
            }
        }
    }
}

// ------------------------------------------------------- conv fallback ----
// Round-0 kernel (128-pixel tile, in-kernel fp32->bf16 split staging).
template<bool PRE>
__global__ __launch_bounds__(256, 2) void k_conv_fb(const float* __restrict__ x,
        const u16* __restrict__ wh_t,
        const float* __restrict__ bank,
        const float* __restrict__ aws,
        float* __restrict__ out) {
    const int pt    = blockIdx.x;
    const int coblk = blockIdx.y;
    const int b     = blockIdx.z;

    const int tid  = threadIdx.x;
    const int wave = tid >> 6;
    const int lane = tid & 63;
    const int wm = wave >> 1, wn = wave & 1;

    __shared__ u16 xs[2][6 * 58 * 32];

    const int pix0 = pt * 128;
    const int h0   = pix0 / 56;
    const int rlo  = h0 - 1;

    const float* xb = x + (size_t)b * CIN * NPIX;

    int bbase[4], pl[4];
    #pragma unroll
    for (int nf = 0; nf < 4; ++nf) {
        int p = pix0 + wn * 64 + nf * 16 + (lane & 15);
        pl[nf] = p;
        int pc = p < NPIX ? p : NPIX - 1;
        int hp = pc / 56, wp = pc - (pc / 56) * 56;
        bbase[nf] = ((hp - h0) * 58 + wp) * 64 + (lane >> 4) * 16;
    }

    const int cof_base = coblk * 8 + wm * 4;
    float a0 = 0.f, a1 = 0.f, a2 = 0.f, a3 = 0.f;
    if (!PRE) {
        a0 = aws[b * 4 + 0]; a1 = aws[b * 4 + 1];
        a2 = aws[b * 4 + 2]; a3 = aws[b * 4 + 3];
    }

    f32x4 acc[4][4];
    #pragma unroll
    for (int i = 0; i < 4; ++i)
        #pragma unroll
        for (int j = 0; j < 4; ++j) { f32x4 z = {0.f, 0.f, 0.f, 0.f}; acc[i][j] = z; }

    for (int cis = 0; cis < 8; ++cis) {
        const int ci0 = cis * 32;
        __syncthreads();
        for (int idx = tid; idx < 1392; idx += 256) {
            int oct = idx / 348;
            int rc  = idx - oct * 348;
            int row = rc / 58, col = rc - row * 58;
            int hin = rlo + row, win = col - 1;
            U4 uh; uh.x = 0; uh.y = 0; uh.z = 0; uh.w = 0;
            U4 ul = uh;
            if (hin >= 0 && hin < 56 && win >= 0 && win < 56) {
                const float* g = xb + (size_t)(ci0 + oct * 8) * NPIX + hin * 56 + win;
                u16 eh[8], el[8];
                #pragma unroll
                for (int i = 0; i < 8; ++i) {
                    float v = g[(size_t)i * NPIX];
                    u16 h = f2bf(v);
                    eh[i] = h;
                    el[i] = f2bf(v - bf2f(h));
                }
                uh.x = (u32)eh[0] | ((u32)eh[1] << 16);
                uh.y = (u32)eh[2] | ((u32)eh[3] << 16);
                uh.z = (u32)eh[4] | ((u32)eh[5] << 16);
                uh.w = (u32)eh[6] | ((u32)eh[7] << 16);
                ul.x = (u32)el[0] | ((u32)el[1] << 16);
                ul.y = (u32)el[2] | ((u32)el[3] << 16);
                ul.z = (u32)el[4] | ((u32)el[5] << 16);
                ul.w = (u32)el[6] | ((u32)el[7] << 16);
            }
            *(U4*)(&xs[0][rc * 32 + oct * 8]) = uh;
            *(U4*)(&xs[1][rc * 32 + oct * 8]) = ul;
        }
        __syncthreads();

        #pragma unroll
        for (int t = 0; t < 9; ++t) {
            const int ty = t / 3, tx = t - (t / 3) * 3;
            bf16x8 ah[4], al[4];
            if (PRE) {
                #pragma unroll
                for (int mf = 0; mf < 4; ++mf) {
                    size_t off = ((((size_t)b * 16 + cof_base + mf) * 9 + t) * 8 + cis) * 512
                               + (size_t)lane * 8;
                    ah[mf] = *(const bf16x8*)(wh_t + off);
                    al[mf] = *(const bf16x8*)(wh_t + WF_N + off);
                }
            } else {
                #pragma unroll
                for (int mf = 0; mf < 4; ++mf) {
                    int co = coblk * 128 + wm * 64 + mf * 16 + (lane & 15);
                    int q = lane >> 4;
                    u16 ph[8], plo[8];
                    #pragma unroll
                    for (int jj = 0; jj < 8; ++jj) {
                        int ci = ci0 + q * 8 + jj;
                        size_t base = ((size_t)co * CIN + ci) * 9 + t;
                        float w = a0 * bank[base]
                                + a1 * bank[base + BANK_SZ]
                                + a2 * bank[base + 2 * BANK_SZ]
                                + a3 * bank[base + 3 * BANK_SZ];
                        u16 h = f2bf(w);
                        ph[jj]  = h;
                        plo[jj] = f2bf(w - bf2f(h));
                    }
                    union { U4 u; bf16x8 v; } pu;
                    pu.u.x = (u32)ph[0] | ((u32)ph[1] << 16);
                    pu.u.y = (u32)ph[2] | ((u32)ph[3] << 16);
                    pu.u.z = (u32)ph[4] | ((u32)ph[5] << 16);
                    pu.u.w = (u32)ph[6] | ((u32)ph[7] << 16);
                    ah[mf] = pu.v;
                    pu.u.x = (u32)plo[0] | ((u32)plo[1] << 16);
                    pu.u.y = (u32)plo[2] | ((u32)plo[3] << 16);
                    pu.u.z = (u32)plo[4] | ((u32)plo[5] << 16);
                    pu.u.w = (u32)plo[6] | ((u32)plo[7] << 16);
                    al[mf] = pu.v;
                }
            }
            const int toff = (ty * 58 + tx) * 64;
            #pragma unroll
            for (int nf = 0; nf < 4; ++nf) {
                bf16x8 bh = *(const bf16x8*)((const char*)&xs[0][0] + bbase[nf] + toff);
                bf16x8 bl = *(const bf16x8*)((const char*)&xs[1][0] + bbase[nf] + toff);
                #pragma unroll
                for (int mf = 0; mf < 4; ++mf) {
                    acc[mf][nf] = __builtin_amdgcn_mfma_f32_16x16x32_bf16(
                        ah[mf], bh, acc[mf][nf], 0, 0, 0);
                    acc[mf][nf] = __builtin_amdgcn_mfma_f32_16x16x32_bf16(
                        ah[mf], bl, acc[mf][nf], 0, 0, 0);
                    acc[mf][nf] = __builtin_amdgcn_mfma_f32_16x16x32_bf16(
                        al[mf], bh, acc[mf][nf], 0, 0, 0);
                }
            }
        }
    }

    float* ob = out + (size_t)b * COUT * NPIX;
    #pragma unroll
    for (int mf = 0; mf < 4; ++mf) {
        int cobase = coblk * 128 + wm * 64 + mf * 16 + (lane >> 4) * 4;
        #pragma unroll
        for (int nf = 0; nf < 4; ++nf) {
            int p = pl[nf];
            if (p < NPIX) {
                #pragma unroll
                for (int r = 0; r < 4; ++r)
                    ob[(size_t)(cobase + r) * NPIX + p] = acc[mf][nf][r];
            }
        }
    }
}

// -------------------------------------------------------------- launch ----
extern "C" void kernel_launch(void* const* d_in, const int* in_sizes, int n_in,
                              void* d_out, int out_size, void* d_ws, size_t ws_size,
                              hipStream_t stream) {
    const float* x    = (const float*)d_in[0];
    const float* bank = (const float*)d_in[1];
    const float* fc1w = (const float*)d_in[2];
    const float* fc1b = (const float*)d_in[3];
    const float* fc2w = (const float*)d_in[4];
    const float* fc2b = (const float*)d_in[5];
    float* out = (float*)d_out;

    float* a_ws = (float*)d_ws;                 // 128 floats @ 0
    float* v_ws = (float*)d_ws + 128;           // 8192 floats @ 512B
    u16*   wf   = (u16*)((char*)d_ws + 65536);  // 2 x 37.75 MB premixed hi/lo
    u16*   xsp  = (u16*)((char*)d_ws + 65536 + (size_t)WF_N * 2 * sizeof(u16));

    const size_t need1 = (size_t)65536 + (size_t)WF_N * 2 * sizeof(u16);
    const size_t need2 = need1 + (size_t)XSP_HALF * 2 * sizeof(u16);

    k_mean<<<dim3(B_SZ * CIN), dim3(64), 0, stream>>>(x, v_ws);
    k_router<<<dim3(B_SZ), dim3(64), 0, stream>>>(v_ws, fc1w, fc1b, fc2w, fc2b, a_ws);

    if (ws_size >= need2) {
        k_premix<<<dim3(256, B_SZ), dim3(256), 0, stream>>>(bank, a_ws, wf);
        k_split<<<dim3(B_SZ * 8 * XROWS), dim3(256), 0, stream>>>(x, xsp);
        k_conv2<<<dim3(13, 2, B_SZ), dim3(256), 0, stream>>>(wf, xsp, out);
    } else if (ws_size >= need1) {
        k_premix<<<dim3(256, B_SZ), dim3(256), 0, stream>>>(bank, a_ws, wf);
        k_conv_fb<true><<<dim3(25, 2, B_SZ), dim3(256), 0, stream>>>(x, wf, bank, a_ws, out);
    } else {
        k_conv_fb<false><<<dim3(25, 2, B_SZ), dim3(256), 0, stream>>>(x, wf, bank, a_ws, out);
    }
}

// Round 4
// 563.831 us; speedup vs baseline: 1.3629x; 1.3151x over previous
//
#include <hip/hip_runtime.h>
#include <stdint.h>

typedef unsigned short u16;
typedef unsigned int   u32;

#define B_SZ  32
#define CIN   256
#define NPIX  3136      // 56*56
#define COUT  256
#define HID   64
#define NBANK 4
#define BANK_SZ 589824  // COUT*CIN*9 elements per bank (fp32)
#define WF_N  18874368  // premixed elements per half: 32*16*9*8*512

// pre-split x planes: [b][cis(8)][row(64)][ciq(4)][col(64)][ci8(8)] u16
// (row = hin+1; rows 0 and 57..63 zero; col = win+1, cols 0,57..63 zero)
#define XROWS 64
#define XSP_HALF 33554432ull    // 32*8*64*2048 elements per half

typedef short bf16x8 __attribute__((ext_vector_type(8)));
typedef float f32x4  __attribute__((ext_vector_type(4)));

struct __align__(16) U4 { u32 x, y, z, w; };
struct __align__(16) F4 { float x, y, z, w; };

__device__ __forceinline__ float bf2f(u16 u) {
    union { u32 i; float f; } v; v.i = ((u32)u) << 16; return v.f;
}
__device__ __forceinline__ u16 f2bf(float f) {
    union { float f; u32 i; } v; v.f = f;
    u32 u = v.i;
    return (u16)((u + 0x7FFFu + ((u >> 16) & 1u)) >> 16);   // RNE
}

__device__ __forceinline__ void gload_lds16(const u16* g, u16* l) {
    __builtin_amdgcn_global_load_lds(
        (const __attribute__((address_space(1))) void*)g,
        (__attribute__((address_space(3))) void*)l, 16, 0, 0);
}

// ---------------------------------------------------------------- mean ----
__global__ __launch_bounds__(64) void k_mean(const float* __restrict__ x,
                                             float* __restrict__ vout) {
    int bc = blockIdx.x;
    const F4* p = (const F4*)(x + (size_t)bc * NPIX);
    float s = 0.f;
    for (int o = threadIdx.x; o < 784; o += 64) {   // 784*4 = 3136
        F4 u = p[o];
        s += u.x + u.y + u.z + u.w;
    }
    #pragma unroll
    for (int off = 32; off > 0; off >>= 1) s += __shfl_down(s, off, 64);
    if (threadIdx.x == 0) vout[bc] = s * (1.0f / 3136.0f);
}

// -------------------------------------------------------------- router ----
__global__ __launch_bounds__(64) void k_router(const float* __restrict__ v,
        const float* __restrict__ fc1w, const float* __restrict__ fc1b,
        const float* __restrict__ fc2w, const float* __restrict__ fc2b,
        float* __restrict__ aout) {
    int b = blockIdx.x, j = threadIdx.x;
    __shared__ float hl[HID];
    __shared__ float lg[NBANK];
    const float* vb = v + b * CIN;
    float acc = fc1b[j];
    const F4* wrow = (const F4*)(fc1w + j * CIN);
    for (int o = 0; o < 64; ++o) {
        F4 u = wrow[o];
        acc += vb[o * 4 + 0] * u.x + vb[o * 4 + 1] * u.y
             + vb[o * 4 + 2] * u.z + vb[o * 4 + 3] * u.w;
    }
    hl[j] = acc > 0.f ? acc : 0.f;
    __syncthreads();
    if (j < NBANK) {
        float l = fc2b[j];
        for (int t = 0; t < HID; ++t) l += hl[t] * fc2w[j * HID + t];
        lg[j] = l;
    }
    __syncthreads();
    if (j == 0) {
        float m = lg[0];
        for (int k = 1; k < NBANK; ++k) m = fmaxf(m, lg[k]);
        float e[NBANK], se = 0.f;
        for (int k = 0; k < NBANK; ++k) { e[k] = expf(lg[k] - m); se += e[k]; }
        for (int k = 0; k < NBANK; ++k) aout[b * NBANK + k] = e[k] / se;
    }
}

// --------------------------------------------------------------- split ----
// One block per (b, cis, row). Row layout: [ciq(4)][col(64)][ci8(8)] u16
// so a wave's 64 lanes read consecutive 16B atoms (conflict-free ds_read).
__global__ __launch_bounds__(256) void k_split(const float* __restrict__ x,
                                               u16* __restrict__ xsp) {
    const int blk = blockIdx.x;            // ((b*8)+cis)*64 + row
    const int row = blk & 63;
    const int bc  = blk >> 6;
    const int b   = bc >> 3, cis = bc & 7;
    const int t   = threadIdx.x;
    const size_t obase = (size_t)blk * 2048;   // 2048 u16 per row
    const int hin = row - 1;
    if (hin < 0 || hin >= 56) {
        U4 z; z.x = 0; z.y = 0; z.z = 0; z.w = 0;
        *(U4*)(xsp + obase + (size_t)t * 8) = z;
        *(U4*)(xsp + XSP_HALF + obase + (size_t)t * 8) = z;
        return;
    }
    __shared__ float ls[32 * 57];   // [ci][56 + pad]
    const float* xb = x + ((size_t)b * CIN + cis * 32) * NPIX + hin * 56;
    for (int idx = t; idx < 448; idx += 256) {     // 32 ci x 14 F4
        int ci = idx / 14, o = idx - ci * 14;
        F4 u = *(const F4*)(xb + (size_t)ci * NPIX + o * 4);
        float* d = &ls[ci * 57 + o * 4];
        d[0] = u.x; d[1] = u.y; d[2] = u.z; d[3] = u.w;
    }
    __syncthreads();
    const int ci2 = (t & 15) * 2;     // even ci
    const int cg  = t >> 4;           // 0..15
    const int ciq = ci2 >> 3;
    const int cil = ci2 & 7;
    #pragma unroll
    for (int k = 0; k < 4; ++k) {
        int col = cg + k * 16;
        int win = col - 1;
        float v0 = 0.f, v1 = 0.f;
        if (win >= 0 && win < 56) {
            v0 = ls[ci2 * 57 + win];
            v1 = ls[(ci2 + 1) * 57 + win];
        }
        u16 h0 = f2bf(v0), h1 = f2bf(v1);
        u16 l0 = f2bf(v0 - bf2f(h0)), l1 = f2bf(v1 - bf2f(h1));
        size_t pos = obase + (size_t)(ciq * 64 + col) * 8 + cil;
        *(u32*)(xsp + pos)            = (u32)h0 | ((u32)h1 << 16);
        *(u32*)(xsp + XSP_HALF + pos) = (u32)l0 | ((u32)l1 << 16);
    }
}

// -------------------------------------------------------------- premix ----
// grid (256, 32): x = cof*16 + cis16, y = b.
#define PM_PAD 145
__global__ __launch_bounds__(256) void k_premix(const float* __restrict__ bank,
        const float* __restrict__ aws, u16* __restrict__ wf) {
    int cof   = blockIdx.x >> 4;
    int cis16 = blockIdx.x & 15;
    int b     = blockIdx.y;
    __shared__ float lw[64 * PM_PAD];
    for (int idx = threadIdx.x; idx < 64 * 144; idx += 256) {
        int s = idx / 144;
        int e = idx - s * 144;
        int k = s >> 4, co_l = s & 15;
        lw[s * PM_PAD + e] =
            bank[(size_t)(k * COUT + cof * 16 + co_l) * (CIN * 9) + cis16 * 144 + e];
    }
    __syncthreads();
    const int cis   = cis16 >> 1;
    const int qbase = (cis16 & 1) * 2;
    float a0 = aws[b * 4 + 0], a1 = aws[b * 4 + 1];
    float a2 = aws[b * 4 + 2], a3 = aws[b * 4 + 3];
    for (int o = threadIdx.x; o < 288; o += 256) {
        int t  = o >> 5;
        int hlane = o & 31;
        int lane  = qbase * 16 + hlane;
        int m = lane & 15, q = lane >> 4;
        int q_loc = q - qbase;
        u16 ph[8], plo[8];
        #pragma unroll
        for (int jj = 0; jj < 8; ++jj) {
            int ee = (q_loc * 8 + jj) * 9 + t;
            float w = a0 * lw[(0 * 16 + m) * PM_PAD + ee]
                    + a1 * lw[(1 * 16 + m) * PM_PAD + ee]
                    + a2 * lw[(2 * 16 + m) * PM_PAD + ee]
                    + a3 * lw[(3 * 16 + m) * PM_PAD + ee];
            u16 h = f2bf(w);
            ph[jj]  = h;
            plo[jj] = f2bf(w - bf2f(h));
        }
        size_t off = ((((size_t)b * 16 + cof) * 9 + t) * 8 + cis) * 512
                   + (size_t)lane * 8;
        U4 uh, ul;
        uh.x = (u32)ph[0] | ((u32)ph[1] << 16);
        uh.y = (u32)ph[2] | ((u32)ph[3] << 16);
        uh.z = (u32)ph[4] | ((u32)ph[5] << 16);
        uh.w = (u32)ph[6] | ((u32)ph[7] << 16);
        ul.x = (u32)plo[0] | ((u32)plo[1] << 16);
        ul.y = (u32)plo[2] | ((u32)plo[3] << 16);
        ul.z = (u32)plo[4] | ((u32)plo[5] << 16);
        ul.w = (u32)plo[6] | ((u32)plo[7] << 16);
        *(U4*)(wf + off)        = uh;
        *(U4*)(wf + WF_N + off) = ul;
    }
}

// ---------------------------------------------------------------- conv ----
// 256-pixel tile, half-plane (hi/lo) double-buffered x pipeline, PLUS
// depth-1 register double-buffer on the weight stream (the r3 stall), PLUS
// bijective XCD b-affinity swizzle (all 26 blocks of a b on one XCD's L2).
__global__ __launch_bounds__(256, 2) void k_conv2(
        const u16* __restrict__ wh_t,     // premixed hi; lo at +WF_N
        const u16* __restrict__ xsp,      // pre-split x hi; lo at +XSP_HALF
        float* __restrict__ out) {
    __shared__ u16 xbuf[2][16384];        // 2 x 32 KiB planes

    // ---- XCD b-affinity swizzle: 832 = 8 XCDs x (4 b x 26 blocks) ----
    const int flat = blockIdx.x;
    const int g    = flat & 7;            // XCD (round-robin dispatch)
    const int idx  = flat >> 3;           // 0..103
    const int b    = g * 4 + (idx / 26);  // 4 b's per XCD
    const int r    = idx % 26;
    const int coblk = r / 13;             // 0..1
    const int pt    = r % 13;             // 0..12

    const int tid  = threadIdx.x;
    const int wave = tid >> 6;
    const int lane = tid & 63;
    const int wm = wave >> 1, wn = wave & 1;

    const int pix0 = pt * 256;
    const int h0   = pix0 / 56;

    // staging source base for (b, cis=0, hi); cis step = 131072 u16
    const size_t rowbase = (((size_t)b * 8) * 64 + h0) * 2048;

    int bb[8], pl[8];
    #pragma unroll
    for (int nf = 0; nf < 8; ++nf) {
        int p = pix0 + wn * 128 + nf * 16 + (lane & 15);
        pl[nf] = p;
        int pc = p < NPIX ? p : NPIX - 1;
        int hp = pc / 56, wp = pc - (pc / 56) * 56;
        // byte offset: [(row)(4 ciq)(64 col)] * 16B atoms
        bb[nf] = ((hp - h0) * 256 + (lane >> 4) * 64 + wp) * 16;
    }

    const u16* wbase = wh_t
        + ((size_t)b * 16 + coblk * 8 + wm * 4) * (9 * 8 * 512)
        + (size_t)lane * 8;

    f32x4 acc[4][8];
    #pragma unroll
    for (int i = 0; i < 4; ++i)
        #pragma unroll
        for (int j = 0; j < 8; ++j) { f32x4 z = {0.f, 0.f, 0.f, 0.f}; acc[i][j] = z; }

    // ---- prologue: stage (cis0, hi) -> buf0 ----
    {
        const u16* sb = xsp + rowbase;
        #pragma unroll
        for (int c = wave; c < 32; c += 4)
            gload_lds16(sb + c * 512 + lane * 8, &xbuf[0][c * 512 + lane * 8]);
    }

    for (int cis = 0; cis < 8; ++cis) {
        // ================= HI phase (x-hi plane in buf0) =================
        asm volatile("s_waitcnt vmcnt(0) lgkmcnt(0)" ::: "memory");
        __builtin_amdgcn_s_barrier();
        __builtin_amdgcn_sched_barrier(0);
        {   // issue lo-plane of this cis -> buf1
            const u16* sb = xsp + XSP_HALF + rowbase + (size_t)cis * 131072;
            #pragma unroll
            for (int c = wave; c < 32; c += 4)
                gload_lds16(sb + c * 512 + lane * 8, &xbuf[1][c * 512 + lane * 8]);
        }
        __builtin_amdgcn_sched_barrier(0);
        {
            // depth-1 weight double-buffer: load t+1 while t's MFMAs issue
            bf16x8 wh[2][4], wl[2][4];
            #pragma unroll
            for (int mf = 0; mf < 4; ++mf) {
                size_t off = (size_t)((mf * 9 + 0) * 8 + cis) * 512;
                wh[0][mf] = *(const bf16x8*)(wbase + off);
                wl[0][mf] = *(const bf16x8*)(wbase + WF_N + off);
            }
            #pragma unroll
            for (int t = 0; t < 9; ++t) {
                const int cur = t & 1, nxt = cur ^ 1;
                if (t < 8) {
                    #pragma unroll
                    for (int mf = 0; mf < 4; ++mf) {
                        size_t off = (size_t)((mf * 9 + t + 1) * 8 + cis) * 512;
                        wh[nxt][mf] = *(const bf16x8*)(wbase + off);
                        wl[nxt][mf] = *(const bf16x8*)(wbase + WF_N + off);
                    }
                }
                const int ty = t / 3, tx = t - ty * 3;
                const int toff = ty * 4096 + tx * 16;
                __builtin_amdgcn_s_setprio(1);
                #pragma unroll
                for (int nf = 0; nf < 8; ++nf) {
                    bf16x8 bx = *(const bf16x8*)((const char*)&xbuf[0][0] + bb[nf] + toff);
                    #pragma unroll
                    for (int mf = 0; mf < 4; ++mf) {
                        acc[mf][nf] = __builtin_amdgcn_mfma_f32_16x16x32_bf16(
                            wh[cur][mf], bx, acc[mf][nf], 0, 0, 0);
                        acc[mf][nf] = __builtin_amdgcn_mfma_f32_16x16x32_bf16(
                            wl[cur][mf], bx, acc[mf][nf], 0, 0, 0);
                    }
                }
                __builtin_amdgcn_s_setprio(0);
            }
        }
        // ================= LO phase (x-lo plane in buf1) =================
        asm volatile("s_waitcnt vmcnt(0) lgkmcnt(0)" ::: "memory");
        __builtin_amdgcn_s_barrier();
        __builtin_amdgcn_sched_barrier(0);
        if (cis < 7) {   // issue hi-plane of cis+1 -> buf0
            const u16* sb = xsp + rowbase + (size_t)(cis + 1) * 131072;
            #pragma unroll
            for (int c = wave; c < 32; c += 4)
                gload_lds16(sb + c * 512 + lane * 8, &xbuf[0][c * 512 + lane * 8]);
        }
        __builtin_amdgcn_sched_barrier(0);
        {
            bf16x8 wlo[2][4];
            #pragma unroll
            for (int mf = 0; mf < 4; ++mf) {
                size_t off = (size_t)((mf * 9 + 0) * 8 + cis) * 512;
                wlo[0][mf] = *(const bf16x8*)(wbase + off);   // hi weights
            }
            #pragma unroll
            for (int t = 0; t < 9; ++t) {
                const int cur = t & 1, nxt = cur ^ 1;
                if (t < 8) {
                    #pragma unroll
                    for (int mf = 0; mf < 4; ++mf) {
                        size_t off = (size_t)((mf * 9 + t + 1) * 8 + cis) * 512;
                        wlo[nxt][mf] = *(const bf16x8*)(wbase + off);
                    }
                }
                const int ty = t / 3, tx = t - ty * 3;
                const int toff = ty * 4096 + tx * 16;
                __builtin_amdgcn_s_setprio(1);
                #pragma unroll
                for (int nf = 0; nf < 8; ++nf) {
                    bf16x8 bx = *(const bf16x8*)((const char*)&xbuf[1][0] + bb[nf] + toff);
                    #pragma unroll
                    for (int mf = 0; mf < 4; ++mf) {
                        acc[mf][nf] = __builtin_amdgcn_mfma_f32_16x16x32_bf16(
                            wlo[cur][mf], bx, acc[mf][nf], 0, 0, 0);
                    }
                }
                __builtin_amdgcn_s_setprio(0);
            }
        }
    }

    // ---- epilogue: C/D layout col(pixel)=lane&15, row(co)=(lane>>4)*4+r ----
    float* ob = out + (size_t)b * COUT * NPIX;
    #pragma unroll
    for (int mf = 0; mf < 4; ++mf) {
        int cobase = coblk * 128 + wm * 64 + mf * 16 + (lane >> 4) * 4;
        #pragma unroll
        for (int nf = 0; nf < 8; ++nf) {
            int p = pl[nf];
            if (p < NPIX) {
                #pragma unroll
                for (int r = 0; r < 4; ++r)
                    ob[(size_t)(cobase + r) * NPIX + p] = acc[mf][nf][r];
            }
        }
    }
}

// ------------------------------------------------------- conv fallback ----
// Round-0 kernel (128-pixel tile, in-kernel fp32->bf16 split staging).
template<bool PRE>
__global__ __launch_bounds__(256, 2) void k_conv_fb(const float* __restrict__ x,
        const u16* __restrict__ wh_t,
        const float* __restrict__ bank,
        const float* __restrict__ aws,
        float* __restrict__ out) {
    const int pt    = blockIdx.x;
    const int coblk = blockIdx.y;
    const int b     = blockIdx.z;

    const int tid  = threadIdx.x;
    const int wave = tid >> 6;
    const int lane = tid & 63;
    const int wm = wave >> 1, wn = wave & 1;

    __shared__ u16 xs[2][6 * 58 * 32];

    const int pix0 = pt * 128;
    const int h0   = pix0 / 56;
    const int rlo  = h0 - 1;

    const float* xb = x + (size_t)b * CIN * NPIX;

    int bbase[4], pl[4];
    #pragma unroll
    for (int nf = 0; nf < 4; ++nf) {
        int p = pix0 + wn * 64 + nf * 16 + (lane & 15);
        pl[nf] = p;
        int pc = p < NPIX ? p : NPIX - 1;
        int hp = pc / 56, wp = pc - (pc / 56) * 56;
        bbase[nf] = ((hp - h0) * 58 + wp) * 64 + (lane >> 4) * 16;
    }

    const int cof_base = coblk * 8 + wm * 4;
    float a0 = 0.f, a1 = 0.f, a2 = 0.f, a3 = 0.f;
    if (!PRE) {
        a0 = aws[b * 4 + 0]; a1 = aws[b * 4 + 1];
        a2 = aws[b * 4 + 2]; a3 = aws[b * 4 + 3];
    }

    f32x4 acc[4][4];
    #pragma unroll
    for (int i = 0; i < 4; ++i)
        #pragma unroll
        for (int j = 0; j < 4; ++j) { f32x4 z = {0.f, 0.f, 0.f, 0.f}; acc[i][j] = z; }

    for (int cis = 0; cis < 8; ++cis) {
        const int ci0 = cis * 32;
        __syncthreads();
        for (int idx = tid; idx < 1392; idx += 256) {
            int oct = idx / 348;
            int rc  = idx - oct * 348;
            int row = rc / 58, col = rc - row * 58;
            int hin = rlo + row, win = col - 1;
            U4 uh; uh.x = 0; uh.y = 0; uh.z = 0; uh.w = 0;
            U4 ul = uh;
            if (hin >= 0 && hin < 56 && win >= 0 && win < 56) {
                const float* g = xb + (size_t)(ci0 + oct * 8) * NPIX + hin * 56 + win;
                u16 eh[8], el[8];
                #pragma unroll
                for (int i = 0; i < 8; ++i) {
                    float v = g[(size_t)i * NPIX];
                    u16 h = f2bf(v);
                    eh[i] = h;
                    el[i] = f2bf(v - bf2f(h));
                }
                uh.x = (u32)eh[0] | ((u32)eh[1] << 16);
                uh.y = (u32)eh[2] | ((u32)eh[3] << 16);
                uh.z = (u32)eh[4] | ((u32)eh[5] << 16);
                uh.w = (u32)eh[6] | ((u32)eh[7] << 16);
                ul.x = (u32)el[0] | ((u32)el[1] << 16);
                ul.y = (u32)el[2] | ((u32)el[3] << 16);
                ul.z = (u32)el[4] | ((u32)el[5] << 16);
                ul.w = (u32)el[6] | ((u32)el[7] << 16);
            }
            *(U4*)(&xs[0][rc * 32 + oct * 8]) = uh;
            *(U4*)(&xs[1][rc * 32 + oct * 8]) = ul;
        }
        __syncthreads();

        #pragma unroll
        for (int t = 0; t < 9; ++t) {
            const int ty = t / 3, tx = t - (t / 3) * 3;
            bf16x8 ah[4], al[4];
            if (PRE) {
                #pragma unroll
                for (int mf = 0; mf < 4; ++mf) {
                    size_t off = ((((size_t)b * 16 + cof_base + mf) * 9 + t) * 8 + cis) * 512
                               + (size_t)lane * 8;
                    ah[mf] = *(const bf16x8*)(wh_t + off);
                    al[mf] = *(const bf16x8*)(wh_t + WF_N + off);
                }
            } else {
                #pragma unroll
                for (int mf = 0; mf < 4; ++mf) {
                    int co = coblk * 128 + wm * 64 + mf * 16 + (lane & 15);
                    int q = lane >> 4;
                    u16 ph[8], plo[8];
                    #pragma unroll
                    for (int jj = 0; jj < 8; ++jj) {
                        int ci = ci0 + q * 8 + jj;
                        size_t base = ((size_t)co * CIN + ci) * 9 + t;
                        float w = a0 * bank[base]
                                + a1 * bank[base + BANK_SZ]
                                + a2 * bank[base + 2 * BANK_SZ]
                                + a3 * bank[base + 3 * BANK_SZ];
                        u16 h = f2bf(w);
                        ph[jj]  = h;
                        plo[jj] = f2bf(w - bf2f(h));
                    }
                    union { U4 u; bf16x8 v; } pu;
                    pu.u.x = (u32)ph[0] | ((u32)ph[1] << 16);
                    pu.u.y = (u32)ph[2] | ((u32)ph[3] << 16);
                    pu.u.z = (u32)ph[4] | ((u32)ph[5] << 16);
                    pu.u.w = (u32)ph[6] | ((u32)ph[7] << 16);
                    ah[mf] = pu.v;
                    pu.u.x = (u32)plo[0] | ((u32)plo[1] << 16);
                    pu.u.y = (u32)plo[2] | ((u32)plo[3] << 16);
                    pu.u.z = (u32)plo[4] | ((u32)plo[5] << 16);
                    pu.u.w = (u32)plo[6] | ((u32)plo[7] << 16);
                    al[mf] = pu.v;
                }
            }
            const int toff = (ty * 58 + tx) * 64;
            #pragma unroll
            for (int nf = 0; nf < 4; ++nf) {
                bf16x8 bh = *(const bf16x8*)((const char*)&xs[0][0] + bbase[nf] + toff);
                bf16x8 bl = *(const bf16x8*)((const char*)&xs[1][0] + bbase[nf] + toff);
                #pragma unroll
                for (int mf = 0; mf < 4; ++mf) {
                    acc[mf][nf] = __builtin_amdgcn_mfma_f32_16x16x32_bf16(
                        ah[mf], bh, acc[mf][nf], 0, 0, 0);
                    acc[mf][nf] = __builtin_amdgcn_mfma_f32_16x16x32_bf16(
                        ah[mf], bl, acc[mf][nf], 0, 0, 0);
                    acc[mf][nf] = __builtin_amdgcn_mfma_f32_16x16x32_bf16(
                        al[mf], bh, acc[mf][nf], 0, 0, 0);
                }
            }
        }
    }

    float* ob = out + (size_t)b * COUT * NPIX;
    #pragma unroll
    for (int mf = 0; mf < 4; ++mf) {
        int cobase = coblk * 128 + wm * 64 + mf * 16 + (lane >> 4) * 4;
        #pragma unroll
        for (int nf = 0; nf < 4; ++nf) {
            int p = pl[nf];
            if (p < NPIX) {
                #pragma unroll
                for (int r = 0; r < 4; ++r)
                    ob[(size_t)(cobase + r) * NPIX + p] = acc[mf][nf][r];
            }
        }
    }
}

// -------------------------------------------------------------- launch ----
extern "C" void kernel_launch(void* const* d_in, const int* in_sizes, int n_in,
                              void* d_out, int out_size, void* d_ws, size_t ws_size,
                              hipStream_t stream) {
    const float* x    = (const float*)d_in[0];
    const float* bank = (const float*)d_in[1];
    const float* fc1w = (const float*)d_in[2];
    const float* fc1b = (const float*)d_in[3];
    const float* fc2w = (const float*)d_in[4];
    const float* fc2b = (const float*)d_in[5];
    float* out = (float*)d_out;

    float* a_ws = (float*)d_ws;                 // 128 floats @ 0
    float* v_ws = (float*)d_ws + 128;           // 8192 floats @ 512B
    u16*   wf   = (u16*)((char*)d_ws + 65536);  // 2 x 37.75 MB premixed hi/lo
    u16*   xsp  = (u16*)((char*)d_ws + 65536 + (size_t)WF_N * 2 * sizeof(u16));

    const size_t need1 = (size_t)65536 + (size_t)WF_N * 2 * sizeof(u16);
    const size_t need2 = need1 + (size_t)XSP_HALF * 2 * sizeof(u16);

    k_mean<<<dim3(B_SZ * CIN), dim3(64), 0, stream>>>(x, v_ws);
    k_router<<<dim3(B_SZ), dim3(64), 0, stream>>>(v_ws, fc1w, fc1b, fc2w, fc2b, a_ws);

    if (ws_size >= need2) {
        k_premix<<<dim3(256, B_SZ), dim3(256), 0, stream>>>(bank, a_ws, wf);
        k_split<<<dim3(B_SZ * 8 * XROWS), dim3(256), 0, stream>>>(x, xsp);
        k_conv2<<<dim3(832), dim3(256), 0, stream>>>(wf, xsp, out);
    } else if (ws_size >= need1) {
        k_premix<<<dim3(256, B_SZ), dim3(256), 0, stream>>>(bank, a_ws, wf);
        k_conv_fb<true><<<dim3(25, 2, B_SZ), dim3(256), 0, stream>>>(x, wf, bank, a_ws, out);
    } else {
        k_conv_fb<false><<<dim3(25, 2, B_SZ), dim3(256), 0, stream>>>(x, wf, bank, a_ws, out);
    }
}

// Round 5
// 349.447 us; speedup vs baseline: 2.1991x; 1.6135x over previous
//
#include <hip/hip_runtime.h>
#include <stdint.h>

typedef unsigned short u16;
typedef unsigned int   u32;

#define B_SZ  32
#define CIN   256
#define NPIX  3136      // 56*56
#define COUT  256
#define HID   64
#define NBANK 4
#define BANK_SZ 589824  // COUT*CIN*9 elements per bank (fp32)
#define WF_N  18874368  // premixed f16 elements: 32*16*9*8*512

// pre-split x plane (f16): [b][cis(8)][row(64)][ciq(4)][col(64)][ci8(8)] u16
// (row = hin+1; rows 0 and 57..63 zero; col = win+1, cols 0,57..63 zero)
#define XROWS 64
#define XSP_N 33554432ull    // 32*8*64*2048 elements

typedef _Float16 f16x8 __attribute__((ext_vector_type(8)));
typedef short bf16x8 __attribute__((ext_vector_type(8)));
typedef float f32x4  __attribute__((ext_vector_type(4)));

struct __align__(16) U4 { u32 x, y, z, w; };
struct __align__(16) F4 { float x, y, z, w; };

__device__ __forceinline__ float bf2f(u16 u) {
    union { u32 i; float f; } v; v.i = ((u32)u) << 16; return v.f;
}
__device__ __forceinline__ u16 f2bf(float f) {
    union { float f; u32 i; } v; v.f = f;
    u32 u = v.i;
    return (u16)((u + 0x7FFFu + ((u >> 16) & 1u)) >> 16);   // RNE
}
__device__ __forceinline__ u16 f2h(float f) {
    union { _Float16 h; u16 u; } v; v.h = (_Float16)f;      // v_cvt_f16_f32, RNE
    return v.u;
}

__device__ __forceinline__ void gload_lds16(const u16* g, u16* l) {
    __builtin_amdgcn_global_load_lds(
        (const __attribute__((address_space(1))) void*)g,
        (__attribute__((address_space(3))) void*)l, 16, 0, 0);
}

// ---------------------------------------------------------------- mean ----
__global__ __launch_bounds__(64) void k_mean(const float* __restrict__ x,
                                             float* __restrict__ vout) {
    int bc = blockIdx.x;
    const F4* p = (const F4*)(x + (size_t)bc * NPIX);
    float s = 0.f;
    for (int o = threadIdx.x; o < 784; o += 64) {   // 784*4 = 3136
        F4 u = p[o];
        s += u.x + u.y + u.z + u.w;
    }
    #pragma unroll
    for (int off = 32; off > 0; off >>= 1) s += __shfl_down(s, off, 64);
    if (threadIdx.x == 0) vout[bc] = s * (1.0f / 3136.0f);
}

// -------------------------------------------------------------- router ----
__global__ __launch_bounds__(64) void k_router(const float* __restrict__ v,
        const float* __restrict__ fc1w, const float* __restrict__ fc1b,
        const float* __restrict__ fc2w, const float* __restrict__ fc2b,
        float* __restrict__ aout) {
    int b = blockIdx.x, j = threadIdx.x;
    __shared__ float hl[HID];
    __shared__ float lg[NBANK];
    const float* vb = v + b * CIN;
    float acc = fc1b[j];
    const F4* wrow = (const F4*)(fc1w + j * CIN);
    for (int o = 0; o < 64; ++o) {
        F4 u = wrow[o];
        acc += vb[o * 4 + 0] * u.x + vb[o * 4 + 1] * u.y
             + vb[o * 4 + 2] * u.z + vb[o * 4 + 3] * u.w;
    }
    hl[j] = acc > 0.f ? acc : 0.f;
    __syncthreads();
    if (j < NBANK) {
        float l = fc2b[j];
        for (int t = 0; t < HID; ++t) l += hl[t] * fc2w[j * HID + t];
        lg[j] = l;
    }
    __syncthreads();
    if (j == 0) {
        float m = lg[0];
        for (int k = 1; k < NBANK; ++k) m = fmaxf(m, lg[k]);
        float e[NBANK], se = 0.f;
        for (int k = 0; k < NBANK; ++k) { e[k] = expf(lg[k] - m); se += e[k]; }
        for (int k = 0; k < NBANK; ++k) aout[b * NBANK + k] = e[k] / se;
    }
}

// --------------------------------------------------------------- split ----
// One block per (b, cis, row). Row layout: [ciq(4)][col(64)][ci8(8)] u16 f16.
__global__ __launch_bounds__(256) void k_split(const float* __restrict__ x,
                                               u16* __restrict__ xsp) {
    const int blk = blockIdx.x;            // ((b*8)+cis)*64 + row
    const int row = blk & 63;
    const int bc  = blk >> 6;
    const int b   = bc >> 3, cis = bc & 7;
    const int t   = threadIdx.x;
    const size_t obase = (size_t)blk * 2048;   // 2048 u16 per row
    const int hin = row - 1;
    if (hin < 0 || hin >= 56) {
        U4 z; z.x = 0; z.y = 0; z.z = 0; z.w = 0;
        *(U4*)(xsp + obase + (size_t)t * 8) = z;
        return;
    }
    __shared__ float ls[32 * 57];   // [ci][56 + pad]
    const float* xb = x + ((size_t)b * CIN + cis * 32) * NPIX + hin * 56;
    for (int idx = t; idx < 448; idx += 256) {     // 32 ci x 14 F4
        int ci = idx / 14, o = idx - ci * 14;
        F4 u = *(const F4*)(xb + (size_t)ci * NPIX + o * 4);
        float* d = &ls[ci * 57 + o * 4];
        d[0] = u.x; d[1] = u.y; d[2] = u.z; d[3] = u.w;
    }
    __syncthreads();
    const int ci2 = (t & 15) * 2;     // even ci
    const int cg  = t >> 4;           // 0..15
    const int ciq = ci2 >> 3;
    const int cil = ci2 & 7;
    #pragma unroll
    for (int k = 0; k < 4; ++k) {
        int col = cg + k * 16;
        int win = col - 1;
        float v0 = 0.f, v1 = 0.f;
        if (win >= 0 && win < 56) {
            v0 = ls[ci2 * 57 + win];
            v1 = ls[(ci2 + 1) * 57 + win];
        }
        size_t pos = obase + (size_t)(ciq * 64 + col) * 8 + cil;
        *(u32*)(xsp + pos) = (u32)f2h(v0) | ((u32)f2h(v1) << 16);
    }
}

// -------------------------------------------------------------- premix ----
// grid (256, 4): x = cof*16 + cis16, y = b-group of 8. Bank slice loaded to
// LDS ONCE, then reused for 8 batch samples (was 32x redundant fetch).
#define PM_PAD 145
__global__ __launch_bounds__(256) void k_premix(const float* __restrict__ bank,
        const float* __restrict__ aws, u16* __restrict__ wf) {
    int cof   = blockIdx.x >> 4;
    int cis16 = blockIdx.x & 15;
    int bgrp  = blockIdx.y;
    __shared__ float lw[64 * PM_PAD];
    for (int idx = threadIdx.x; idx < 64 * 144; idx += 256) {
        int s = idx / 144;
        int e = idx - s * 144;
        int k = s >> 4, co_l = s & 15;
        lw[s * PM_PAD + e] =
            bank[(size_t)(k * COUT + cof * 16 + co_l) * (CIN * 9) + cis16 * 144 + e];
    }
    __syncthreads();
    const int cis   = cis16 >> 1;
    const int qbase = (cis16 & 1) * 2;
    for (int b8 = 0; b8 < 8; ++b8) {
        const int b = bgrp * 8 + b8;
        float a0 = aws[b * 4 + 0], a1 = aws[b * 4 + 1];
        float a2 = aws[b * 4 + 2], a3 = aws[b * 4 + 3];
        for (int o = threadIdx.x; o < 288; o += 256) {
            int t  = o >> 5;
            int hlane = o & 31;
            int lane  = qbase * 16 + hlane;
            int m = lane & 15, q = lane >> 4;
            int q_loc = q - qbase;
            u16 ph[8];
            #pragma unroll
            for (int jj = 0; jj < 8; ++jj) {
                int ee = (q_loc * 8 + jj) * 9 + t;
                float w = a0 * lw[(0 * 16 + m) * PM_PAD + ee]
                        + a1 * lw[(1 * 16 + m) * PM_PAD + ee]
                        + a2 * lw[(2 * 16 + m) * PM_PAD + ee]
                        + a3 * lw[(3 * 16 + m) * PM_PAD + ee];
                ph[jj] = f2h(w);
            }
            size_t off = ((((size_t)b * 16 + cof) * 9 + t) * 8 + cis) * 512
                       + (size_t)lane * 8;
            U4 uh;
            uh.x = (u32)ph[0] | ((u32)ph[1] << 16);
            uh.y = (u32)ph[2] | ((u32)ph[3] << 16);
            uh.z = (u32)ph[4] | ((u32)ph[5] << 16);
            uh.w = (u32)ph[6] | ((u32)ph[7] << 16);
            *(U4*)(wf + off) = uh;
        }
    }
}

// ---------------------------------------------------------------- conv ----
// Single-pass fp16 implicit GEMM. 256-pixel tile, double-buffered x plane,
// depth-2 weight register ring, XCD b-affinity swizzle, setprio on MFMA.
__global__ __launch_bounds__(256, 2) void k_conv2(
        const u16* __restrict__ wf,       // premixed f16 weights (MFMA-A layout)
        const u16* __restrict__ xsp,      // pre-split f16 x plane
        float* __restrict__ out) {
    __shared__ u16 xbuf[2][16384];        // 2 x 32 KiB planes

    // ---- XCD b-affinity swizzle: 832 = 8 XCDs x (4 b x 26 blocks) ----
    const int flat = blockIdx.x;
    const int g    = flat & 7;            // XCD (round-robin dispatch)
    const int idx  = flat >> 3;           // 0..103
    const int b    = g * 4 + (idx / 26);  // 4 b's per XCD
    const int r    = idx % 26;
    const int coblk = r / 13;             // 0..1
    const int pt    = r % 13;             // 0..12

    const int tid  = threadIdx.x;
    const int wave = tid >> 6;
    const int lane = tid & 63;
    const int wm = wave >> 1, wn = wave & 1;

    const int pix0 = pt * 256;
    const int h0   = pix0 / 56;

    // staging source base for (b, cis=0); cis step = 131072 u16
    const size_t rowbase = (((size_t)b * 8) * 64 + h0) * 2048;

    int bb[8], pl[8];
    #pragma unroll
    for (int nf = 0; nf < 8; ++nf) {
        int p = pix0 + wn * 128 + nf * 16 + (lane & 15);
        pl[nf] = p;
        int pc = p < NPIX ? p : NPIX - 1;
        int hp = pc / 56, wp = pc - (pc / 56) * 56;
        // byte offset: [(row)(4 ciq)(64 col)] * 16B atoms
        bb[nf] = ((hp - h0) * 256 + (lane >> 4) * 64 + wp) * 16;
    }

    const u16* wbase = wf
        + ((size_t)b * 16 + coblk * 8 + wm * 4) * (9 * 8 * 512)
        + (size_t)lane * 8;

    f32x4 acc[4][8];
    #pragma unroll
    for (int i = 0; i < 4; ++i)
        #pragma unroll
        for (int j = 0; j < 8; ++j) { f32x4 z = {0.f, 0.f, 0.f, 0.f}; acc[i][j] = z; }

    // ---- prologue: stage cis0 -> buf0 ----
    {
        const u16* sb = xsp + rowbase;
        #pragma unroll
        for (int c = wave; c < 32; c += 4)
            gload_lds16(sb + c * 512 + lane * 8, &xbuf[0][c * 512 + lane * 8]);
    }

    for (int cis = 0; cis < 8; ++cis) {
        asm volatile("s_waitcnt vmcnt(0) lgkmcnt(0)" ::: "memory");
        __builtin_amdgcn_s_barrier();
        __builtin_amdgcn_sched_barrier(0);
        if (cis < 7) {   // stage next plane into the other buffer
            const u16* sb = xsp + rowbase + (size_t)(cis + 1) * 131072;
            u16* db = &xbuf[(cis + 1) & 1][0];
            #pragma unroll
            for (int c = wave; c < 32; c += 4)
                gload_lds16(sb + c * 512 + lane * 8, db + c * 512 + lane * 8);
        }
        __builtin_amdgcn_sched_barrier(0);

        const char* xb = (const char*)&xbuf[cis & 1][0];
        // depth-2 weight register ring (full unroll -> static indices)
        f16x8 w[3][4];
        #pragma unroll
        for (int mf = 0; mf < 4; ++mf) {
            w[0][mf] = *(const f16x8*)(wbase + (size_t)((mf * 9 + 0) * 8 + cis) * 512);
            w[1][mf] = *(const f16x8*)(wbase + (size_t)((mf * 9 + 1) * 8 + cis) * 512);
        }
        #pragma unroll
        for (int t = 0; t < 9; ++t) {
            if (t < 7) {
                #pragma unroll
                for (int mf = 0; mf < 4; ++mf)
                    w[(t + 2) % 3][mf] =
                        *(const f16x8*)(wbase + (size_t)((mf * 9 + t + 2) * 8 + cis) * 512);
            }
            const int ty = t / 3, tx = t - ty * 3;
            const int toff = ty * 4096 + tx * 16;
            __builtin_amdgcn_s_setprio(1);
            #pragma unroll
            for (int nf = 0; nf < 8; ++nf) {
                f16x8 bx = *(const f16x8*)(xb + bb[nf] + toff);
                #pragma unroll
                for (int mf = 0; mf < 4; ++mf) {
                    acc[mf][nf] = __builtin_amdgcn_mfma_f32_16x16x32_f16(
                        w[t % 3][mf], bx, acc[mf][nf], 0, 0, 0);
                }
            }
            __builtin_amdgcn_s_setprio(0);
        }
    }

    // ---- epilogue: C/D layout col(pixel)=lane&15, row(co)=(lane>>4)*4+r ----
    float* ob = out + (size_t)b * COUT * NPIX;
    #pragma unroll
    for (int mf = 0; mf < 4; ++mf) {
        int cobase = coblk * 128 + wm * 64 + mf * 16 + (lane >> 4) * 4;
        #pragma unroll
        for (int nf = 0; nf < 8; ++nf) {
            int p = pl[nf];
            if (p < NPIX) {
                #pragma unroll
                for (int r = 0; r < 4; ++r)
                    ob[(size_t)(cobase + r) * NPIX + p] = acc[mf][nf][r];
            }
        }
    }
}

// ------------------------------------------------------- conv fallback ----
// Round-0 kernel (128-pixel tile, on-the-fly bf16 3-pass; no workspace).
__global__ __launch_bounds__(256, 2) void k_conv_fb(const float* __restrict__ x,
        const float* __restrict__ bank,
        const float* __restrict__ aws,
        float* __restrict__ out) {
    const int pt    = blockIdx.x;
    const int coblk = blockIdx.y;
    const int b     = blockIdx.z;

    const int tid  = threadIdx.x;
    const int wave = tid >> 6;
    const int lane = tid & 63;
    const int wm = wave >> 1, wn = wave & 1;

    __shared__ u16 xs[2][6 * 58 * 32];

    const int pix0 = pt * 128;
    const int h0   = pix0 / 56;
    const int rlo  = h0 - 1;

    const float* xb = x + (size_t)b * CIN * NPIX;

    int bbase[4], pl[4];
    #pragma unroll
    for (int nf = 0; nf < 4; ++nf) {
        int p = pix0 + wn * 64 + nf * 16 + (lane & 15);
        pl[nf] = p;
        int pc = p < NPIX ? p : NPIX - 1;
        int hp = pc / 56, wp = pc - (pc / 56) * 56;
        bbase[nf] = ((hp - h0) * 58 + wp) * 64 + (lane >> 4) * 16;
    }

    float a0 = aws[b * 4 + 0], a1 = aws[b * 4 + 1];
    float a2 = aws[b * 4 + 2], a3 = aws[b * 4 + 3];

    f32x4 acc[4][4];
    #pragma unroll
    for (int i = 0; i < 4; ++i)
        #pragma unroll
        for (int j = 0; j < 4; ++j) { f32x4 z = {0.f, 0.f, 0.f, 0.f}; acc[i][j] = z; }

    for (int cis = 0; cis < 8; ++cis) {
        const int ci0 = cis * 32;
        __syncthreads();
        for (int idx = tid; idx < 1392; idx += 256) {
            int oct = idx / 348;
            int rc  = idx - oct * 348;
            int row = rc / 58, col = rc - row * 58;
            int hin = rlo + row, win = col - 1;
            U4 uh; uh.x = 0; uh.y = 0; uh.z = 0; uh.w = 0;
            U4 ul = uh;
            if (hin >= 0 && hin < 56 && win >= 0 && win < 56) {
                const float* gp = xb + (size_t)(ci0 + oct * 8) * NPIX + hin * 56 + win;
                u16 eh[8], el[8];
                #pragma unroll
                for (int i = 0; i < 8; ++i) {
                    float v = gp[(size_t)i * NPIX];
                    u16 h = f2bf(v);
                    eh[i] = h;
                    el[i] = f2bf(v - bf2f(h));
                }
                uh.x = (u32)eh[0] | ((u32)eh[1] << 16);
                uh.y = (u32)eh[2] | ((u32)eh[3] << 16);
                uh.z = (u32)eh[4] | ((u32)eh[5] << 16);
                uh.w = (u32)eh[6] | ((u32)eh[7] << 16);
                ul.x = (u32)el[0] | ((u32)el[1] << 16);
                ul.y = (u32)el[2] | ((u32)el[3] << 16);
                ul.z = (u32)el[4] | ((u32)el[5] << 16);
                ul.w = (u32)el[6] | ((u32)el[7] << 16);
            }
            *(U4*)(&xs[0][rc * 32 + oct * 8]) = uh;
            *(U4*)(&xs[1][rc * 32 + oct * 8]) = ul;
        }
        __syncthreads();

        #pragma unroll
        for (int t = 0; t < 9; ++t) {
            const int ty = t / 3, tx = t - (t / 3) * 3;
            bf16x8 ah[4], al[4];
            #pragma unroll
            for (int mf = 0; mf < 4; ++mf) {
                int co = coblk * 128 + wm * 64 + mf * 16 + (lane & 15);
                int q = lane >> 4;
                u16 ph[8], plo[8];
                #pragma unroll
                for (int jj = 0; jj < 8; ++jj) {
                    int ci = ci0 + q * 8 + jj;
                    size_t base = ((size_t)co * CIN + ci) * 9 + t;
                    float w = a0 * bank[base]
                            + a1 * bank[base + BANK_SZ]
                            + a2 * bank[base + 2 * BANK_SZ]
                            + a3 * bank[base + 3 * BANK_SZ];
                    u16 h = f2bf(w);
                    ph[jj]  = h;
                    plo[jj] = f2bf(w - bf2f(h));
                }
                union { U4 u; bf16x8 v; } pu;
                pu.u.x = (u32)ph[0] | ((u32)ph[1] << 16);
                pu.u.y = (u32)ph[2] | ((u32)ph[3] << 16);
                pu.u.z = (u32)ph[4] | ((u32)ph[5] << 16);
                pu.u.w = (u32)ph[6] | ((u32)ph[7] << 16);
                ah[mf] = pu.v;
                pu.u.x = (u32)plo[0] | ((u32)plo[1] << 16);
                pu.u.y = (u32)plo[2] | ((u32)plo[3] << 16);
                pu.u.z = (u32)plo[4] | ((u32)plo[5] << 16);
                pu.u.w = (u32)plo[6] | ((u32)plo[7] << 16);
                al[mf] = pu.v;
            }
            const int toff = (ty * 58 + tx) * 64;
            #pragma unroll
            for (int nf = 0; nf < 4; ++nf) {
                bf16x8 bh = *(const bf16x8*)((const char*)&xs[0][0] + bbase[nf] + toff);
                bf16x8 bl = *(const bf16x8*)((const char*)&xs[1][0] + bbase[nf] + toff);
                #pragma unroll
                for (int mf = 0; mf < 4; ++mf) {
                    acc[mf][nf] = __builtin_amdgcn_mfma_f32_16x16x32_bf16(
                        ah[mf], bh, acc[mf][nf], 0, 0, 0);
                    acc[mf][nf] = __builtin_amdgcn_mfma_f32_16x16x32_bf16(
                        ah[mf], bl, acc[mf][nf], 0, 0, 0);
                    acc[mf][nf] = __builtin_amdgcn_mfma_f32_16x16x32_bf16(
                        al[mf], bh, acc[mf][nf], 0, 0, 0);
                }
            }
        }
    }

    float* ob = out + (size_t)b * COUT * NPIX;
    #pragma unroll
    for (int mf = 0; mf < 4; ++mf) {
        int cobase = coblk * 128 + wm * 64 + mf * 16 + (lane >> 4) * 4;
        #pragma unroll
        for (int nf = 0; nf < 4; ++nf) {
            int p = pl[nf];
            if (p < NPIX) {
                #pragma unroll
                for (int r = 0; r < 4; ++r)
                    ob[(size_t)(cobase + r) * NPIX + p] = acc[mf][nf][r];
            }
        }
    }
}

// -------------------------------------------------------------- launch ----
extern "C" void kernel_launch(void* const* d_in, const int* in_sizes, int n_in,
                              void* d_out, int out_size, void* d_ws, size_t ws_size,
                              hipStream_t stream) {
    const float* x    = (const float*)d_in[0];
    const float* bank = (const float*)d_in[1];
    const float* fc1w = (const float*)d_in[2];
    const float* fc1b = (const float*)d_in[3];
    const float* fc2w = (const float*)d_in[4];
    const float* fc2b = (const float*)d_in[5];
    float* out = (float*)d_out;

    float* a_ws = (float*)d_ws;                 // 128 floats @ 0
    float* v_ws = (float*)d_ws + 128;           // 8192 floats @ 512B
    u16*   wf   = (u16*)((char*)d_ws + 65536);  // 37.75 MB premixed f16
    u16*   xsp  = (u16*)((char*)d_ws + 65536 + (size_t)WF_N * sizeof(u16));

    const size_t need = (size_t)65536 + (size_t)WF_N * sizeof(u16)
                      + (size_t)XSP_N * sizeof(u16);

    k_mean<<<dim3(B_SZ * CIN), dim3(64), 0, stream>>>(x, v_ws);
    k_router<<<dim3(B_SZ), dim3(64), 0, stream>>>(v_ws, fc1w, fc1b, fc2w, fc2b, a_ws);

    if (ws_size >= need) {
        k_premix<<<dim3(256, 4), dim3(256), 0, stream>>>(bank, a_ws, wf);
        k_split<<<dim3(B_SZ * 8 * XROWS), dim3(256), 0, stream>>>(x, xsp);
        k_conv2<<<dim3(832), dim3(256), 0, stream>>>(wf, xsp, out);
    } else {
        k_conv_fb<<<dim3(25, 2, B_SZ), dim3(256), 0, stream>>>(x, bank, a_ws, out);
    }
}